// Round 2
// baseline (318.565 us; speedup 1.0000x reference)
//
#include <hip/hip_runtime.h>
#include <math.h>

#define F 128
#define THREEF 384
#define N_RBF 20
#define CUTOFF 5.0f
#define CAP 64
#define TLDS_STRIDE 136   // shorts; 272 B row: 16B-aligned, ~2-way banks (free)

typedef __bf16 bf16x8 __attribute__((ext_vector_type(8)));
typedef float  f32x4  __attribute__((ext_vector_type(4)));

// ---------------------------------------------------------------------------
// Prep (fused, block-range sliced):
//   blocks [0, EB)        : build — CSR slot via atomic, pack written directly
//                           at (dst,slot) so gather reads contiguously
//   blocks [EB, EB+256)   : wcast — W1,W2 -> bf16 k-major
//   blocks [EB+256, +8)   : wrt — chunked transpose of Wr for gather
// pack row = {s1, 2cos(x), fcut, ux, uy, uz, src_bits, 0}
// ---------------------------------------------------------------------------
__global__ __launch_bounds__(256) void prep_kernel(
    const float* __restrict__ d_ij, const float* __restrict__ unit_r,
    const int* __restrict__ nbrs,
    const float* __restrict__ W1, const float* __restrict__ W2,
    const float* __restrict__ Wr,
    int* __restrict__ cnt, float* __restrict__ pack,
    __bf16* __restrict__ W1T, __bf16* __restrict__ W2T,
    float* __restrict__ WrT, int E, int EB)
{
    const int tid = threadIdx.x;
    const int b   = blockIdx.x;

    if (b < EB) {                       // ---- build
        const int e = b * 256 + tid;
        if (e >= E) return;
        const int2 nb = ((const int2*)nbrs)[e];
        const int dst = nb.x;
        const int src = nb.y;
        const int slot = atomicAdd(&cnt[dst], 1);
        if (slot >= CAP) return;

        const float d = d_ij[e];
        const float x = (float)M_PI * d * (1.0f / CUTOFF);
        float sx, cx;
        __sincosf(x, &sx, &cx);
        const float fcut = (d < CUTOFF) ? 0.5f * (cx + 1.0f) : 0.0f;
        float4 q0, q1;
        q0.x = sx * fcut / d;           // rbff_1; recurrence keeps fcut/d scale
        q0.y = 2.0f * cx;
        q0.z = fcut;
        q0.w = unit_r[3 * e + 0];
        q1.x = unit_r[3 * e + 1];
        q1.y = unit_r[3 * e + 2];
        q1.z = __int_as_float(src);
        q1.w = 0.0f;
        float4* pk = (float4*)(pack + ((size_t)dst * CAP + slot) * 8);
        pk[0] = q0;
        pk[1] = q1;
    } else if (b < EB + 256) {          // ---- wcast
        const int idx = (b - EB) * 256 + tid;
        if (idx < 128 * 128) {
            const int n = idx >> 7, k = idx & 127;
            W1T[idx] = (__bf16)W1[k * F + n];
        }
        if (idx < 384 * 128) {
            const int n = idx >> 7, k = idx & 127;
            W2T[idx] = (__bf16)W2[k * THREEF + n];
        }
    } else {                            // ---- wrt
        const int idx = (b - EB - 256) * 256 + tid;   // 0..1919
        if (idx >= 5 * 3 * 128) return;
        const int f  = idx & 127;
        const int c  = (idx >> 7) % 3;
        const int n4 = idx / (3 * 128);
        float4 v;
        v.x = Wr[(4 * n4 + 0) * THREEF + c * 128 + f];
        v.y = Wr[(4 * n4 + 1) * THREEF + c * 128 + f];
        v.z = Wr[(4 * n4 + 2) * THREEF + c * 128 + f];
        v.w = Wr[(4 * n4 + 3) * THREEF + c * 128 + f];
        ((float4*)WrT)[idx] = v;
    }
}

// ---------------------------------------------------------------------------
// MLP via bf16 MFMA (fp32 accumulate): phi = silu(h@W1+b1)@W2 + b2.
// R2: phi stored INTERLEAVED as (N,128) float4 {c0,c1,c2,pad} so the gather
// reads one dwordx4 per edge instead of 3 scattered dwords.
// ---------------------------------------------------------------------------
__global__ __launch_bounds__(256) void mlp_mfma_kernel(
    const float* __restrict__ h,      // (N,128) fp32
    const __bf16* __restrict__ W1T,   // (128n,128k)
    const float* __restrict__ b1,     // (128)
    const __bf16* __restrict__ W2T,   // (384n,128k)
    const float* __restrict__ b2,     // (384)
    float* __restrict__ phi, int N)   // (N,128,4) interleaved
{
    __shared__ __bf16 t_lds[4][16 * TLDS_STRIDE];

    const int wave = threadIdx.x >> 6;
    const int lane = threadIdx.x & 63;
    const int m    = lane & 15;
    const int quad = lane >> 4;
    const int node0 = blockIdx.x * 64 + wave * 16;
    if (node0 >= N) return;

    bf16x8 a1[4];
    #pragma unroll
    for (int kb = 0; kb < 4; ++kb) {
        const float* hp = h + (size_t)(node0 + m) * F + kb * 32 + quad * 8;
        const float4 x0 = *(const float4*)hp;
        const float4 x1 = *(const float4*)(hp + 4);
        bf16x8 a;
        a[0] = (__bf16)x0.x; a[1] = (__bf16)x0.y;
        a[2] = (__bf16)x0.z; a[3] = (__bf16)x0.w;
        a[4] = (__bf16)x1.x; a[5] = (__bf16)x1.y;
        a[6] = (__bf16)x1.z; a[7] = (__bf16)x1.w;
        a1[kb] = a;
    }

    #pragma unroll
    for (int ct = 0; ct < 8; ++ct) {
        f32x4 acc = {0.0f, 0.0f, 0.0f, 0.0f};
        #pragma unroll
        for (int kb = 0; kb < 4; ++kb) {
            const bf16x8 b =
                *(const bf16x8*)(W1T + (size_t)(ct * 16 + m) * F + kb * 32 + quad * 8);
            acc = __builtin_amdgcn_mfma_f32_16x16x32_bf16(a1[kb], b, acc, 0, 0, 0);
        }
        const int col = ct * 16 + m;
        const float bb = b1[col];
        #pragma unroll
        for (int reg = 0; reg < 4; ++reg) {
            const float x = acc[reg] + bb;
            const float s = x / (1.0f + __expf(-x));
            t_lds[wave][(quad * 4 + reg) * TLDS_STRIDE + col] = (__bf16)s;
        }
    }

    bf16x8 a2[4];
    #pragma unroll
    for (int kb = 0; kb < 4; ++kb)
        a2[kb] = *(const bf16x8*)&t_lds[wave][m * TLDS_STRIDE + kb * 32 + quad * 8];

    #pragma unroll
    for (int ct = 0; ct < 24; ++ct) {
        f32x4 acc = {0.0f, 0.0f, 0.0f, 0.0f};
        #pragma unroll
        for (int kb = 0; kb < 4; ++kb) {
            const bf16x8 b =
                *(const bf16x8*)(W2T + (size_t)(ct * 16 + m) * F + kb * 32 + quad * 8);
            acc = __builtin_amdgcn_mfma_f32_16x16x32_bf16(a2[kb], b, acc, 0, 0, 0);
        }
        const int col   = ct * 16 + m;
        const int plane = col >> 7;
        const int fc    = col & 127;
        const float bb  = b2[col];
        #pragma unroll
        for (int reg = 0; reg < 4; ++reg) {
            const int row = quad * 4 + reg;
            phi[((((size_t)(node0 + row)) * F + fc) << 2) + plane] = acc[reg] + bb;
        }
    }
}

// ---------------------------------------------------------------------------
// Gather: 256 threads = 2 nodes/block.
// R2 changes vs R1:
//  - w[60] (WrT columns, loop-invariant per thread) pinned in VGPRs via
//    empty inline-asm "+v" — compiler cannot sink/remat the loads anymore.
//  - per-edge RBF recurrence computed ONCE per edge (threads f<deg) into
//    s_rbf LDS at stage time; inner loop reads it via wave-uniform
//    ds_read_b128 broadcast. Removes 20 FMA/edge-thread of redundant work
//    (previously all 128 threads computed identical values).
//  - phi read is a single dwordx4 from the interleaved (N,128,4) layout.
// ---------------------------------------------------------------------------
__global__ __launch_bounds__(256, 4) void gather_kernel(
    const float4* __restrict__ phi4,     // (N,128) quads {c0,c1,c2,pad}
    const float* __restrict__ v_i,       // (N,128,3)
    const float* __restrict__ WrT,       // (5,3,128,4) chunked transpose
    const float* __restrict__ br,        // (384)
    const int*   __restrict__ cnt,       // (N)
    const float* __restrict__ pack,      // (N,CAP,8)
    float* __restrict__ dh,              // (N,128)
    float* __restrict__ dv,              // (N,128,3)
    int N)
{
    __shared__ float4 s_pack[2][CAP * 2];   // 4 KB
    __shared__ float  s_rbf[2][CAP * 20];   // 10.25 KB: 20 rbf values per edge

    const int tid  = threadIdx.x;
    const int half = tid >> 7;
    const int f    = tid & 127;
    const int node = blockIdx.x * 2 + half;

    const int deg0 = cnt[node];
    const int deg  = deg0 < CAP ? deg0 : CAP;

    {   // stage this node's pack rows: deg*2 float4s, coalesced
        const float4* src = (const float4*)(pack + (size_t)node * CAP * 8);
        if (f < 2 * deg) s_pack[half][f] = src[f];
    }

    // loop-invariant Wr columns for this f -> registers (60 VGPRs).
    // asm pins make the values opaque: the loads CANNOT be sunk back into
    // the edge loop (R1 showed source-level hoisting alone gets undone).
    const float4* wTg = (const float4*)WrT;   // wTg[(n4*3 + c)*128 + f]
    float w[60];
    #pragma unroll
    for (int j = 0; j < 15; ++j) {
        const float4 t = wTg[j * 128 + f];
        w[4 * j + 0] = t.x; w[4 * j + 1] = t.y;
        w[4 * j + 2] = t.z; w[4 * j + 3] = t.w;
    }
    #pragma unroll
    for (int j = 0; j < 60; ++j) asm volatile("" : "+v"(w[j]));

    __syncthreads();

    // one thread per edge slot expands the sin-recurrence (identical for all
    // 128 f-threads -> do it once, not 128x)
    if (f < deg) {
        const float* q = (const float*)&s_pack[half][2 * f];
        float rp = 0.0f, rc = q[0];
        const float twoc = q[1];
        float* rb = &s_rbf[half][f * 20];
        rb[0] = rc;
        #pragma unroll
        for (int n = 1; n < 20; ++n) {
            const float rn = fmaf(twoc, rc, -rp);
            rp = rc; rc = rn;
            rb[n] = rc;
        }
    }
    __syncthreads();

    const float br0 = br[f], br1 = br[f + 128], br2 = br[f + 256];

    float dh_acc = 0.0f, dv0 = 0.0f, dv1 = 0.0f, dv2 = 0.0f;

    for (int i = 0; i < deg; ++i) {
        const float* q = (const float*)&s_pack[half][2 * i];
        const float fcut = q[2];
        const float ux   = q[3];
        const float uy   = q[4];
        const float uz   = q[5];
        // LDS value -> SGPR: only lgkmcnt wait, global-load queue stays full
        const int src = __builtin_amdgcn_readfirstlane(__float_as_int(q[6]));

        const float* rb = &s_rbf[half][i * 20];   // wave-uniform broadcast

        float a0 = br0 * fcut, a1 = br1 * fcut, a2 = br2 * fcut;
        #pragma unroll
        for (int n4 = 0; n4 < 5; ++n4) {
            #pragma unroll
            for (int k = 0; k < 4; ++k) {
                const float rn = rb[n4 * 4 + k];
                a0 = fmaf(rn, w[(n4 * 3 + 0) * 4 + k], a0);
                a1 = fmaf(rn, w[(n4 * 3 + 1) * 4 + k], a1);
                a2 = fmaf(rn, w[(n4 * 3 + 2) * 4 + k], a2);
            }
        }

        const float4 ph = phi4[(size_t)src * F + f];
        const float f1 = ph.x * a0;
        const float f2 = ph.y * a1;
        const float f3 = ph.z * a2;

        dh_acc += f3;

        const float* vs = v_i + (size_t)src * THREEF + 3 * f;
        dv0 = fmaf(f1, ux, fmaf(f2, vs[0], dv0));
        dv1 = fmaf(f1, uy, fmaf(f2, vs[1], dv1));
        dv2 = fmaf(f1, uz, fmaf(f2, vs[2], dv2));
    }

    dh[(size_t)node * F + f] = dh_acc;
    float* dvp = dv + (size_t)node * THREEF + 3 * f;
    dvp[0] = dv0;
    dvp[1] = dv1;
    dvp[2] = dv2;
}

extern "C" void kernel_launch(void* const* d_in, const int* in_sizes, int n_in,
                              void* d_out, int out_size, void* d_ws, size_t ws_size,
                              hipStream_t stream) {
    const float* h_i    = (const float*)d_in[0];
    const float* v_i    = (const float*)d_in[1];
    const float* d_ij   = (const float*)d_in[2];
    const float* unit_r = (const float*)d_in[3];
    const int*   nbrs   = (const int*)  d_in[4];
    const float* W1     = (const float*)d_in[5];
    const float* b1     = (const float*)d_in[6];
    const float* W2     = (const float*)d_in[7];
    const float* b2     = (const float*)d_in[8];
    const float* Wr     = (const float*)d_in[9];
    const float* br     = (const float*)d_in[10];

    const int N = in_sizes[0] / F;       // 20000
    const int E = in_sizes[2];           // 320000

    float* dh = (float*)d_out;              // (N,128)
    float* dv = dh + (size_t)N * F;         // (N,128,3)

    // workspace: phi4 (4NF, interleaved) | pack (N*CAP*8) | WrT | cnt | W1T | W2T
    float*  phi  = (float*)d_ws;                           // 41 MB
    float*  pack = phi + (size_t)4 * N * F;                // 41 MB
    float*  WrT  = pack + (size_t)N * CAP * 8;             // 30 KB
    int*    cnt  = (int*)(WrT + 5 * 3 * 128 * 4);          // 80 KB
    __bf16* W1T  = (__bf16*)(cnt + N);                     // 32 KB
    __bf16* W2T  = W1T + 128 * 128;                        // 96 KB

    const int EB = (E + 255) / 256;      // 1250 build blocks

    hipMemsetAsync(cnt, 0, (size_t)N * sizeof(int), stream);

    prep_kernel<<<EB + 256 + 8, 256, 0, stream>>>(
        d_ij, unit_r, nbrs, W1, W2, Wr, cnt, pack, W1T, W2T, WrT, E, EB);
    mlp_mfma_kernel<<<(N + 63) / 64, 256, 0, stream>>>(h_i, W1T, b1, W2T, b2,
                                                       phi, N);
    gather_kernel<<<N / 2, 256, 0, stream>>>((const float4*)phi, v_i, WrT, br,
                                             cnt, pack, dh, dv, N);
}